// Round 8
// baseline (118.461 us; speedup 1.0000x reference)
//
#include <hip/hip_runtime.h>
#include <hip/hip_bf16.h>
#include <stdint.h>

// VQ-VAE vector quantizer forward, MI355X (gfx950).
// z: [32,256,32,32] fp32 (NCHW), E: [1024,256] fp32.
// score(n,k) = 0.5*||e_k||^2 - <f_n,e_k>  (argmin-equivalent to d2)
// dots via bf16 MFMA 16x16x32 fp32-accum; gather exact fp32.
//
// R13: R7-R12 exonerated LDS BW, barrier count, occupancy, HBM. The
// remaining suspect is the per-chunk vmcnt(0) DRAIN inside __syncthreads
// (cf. m233: 2-phase stall = stage+vmcnt+barrier ~72%, untouched by
// removing reads or one barrier -- matches our nulls). Fix = T4 counted
// vmcnt: 4-buffer ring (BK=64), staged 3 chunks ahead, raw s_barrier,
// inline-asm s_waitcnt vmcnt(12) (never 0 until the tail) so loads stay
// in flight ACROSS barriers. Per chunk: vmcnt(12); bar; ds_read+MFMA+
// argmin; lgkmcnt(0); bar; STAGE(ct+4). vmcnt is in-order (m135) so
// <=12 outstanding => chunk-ct's 4 loads landed. lgkmcnt(0) before
// bar-2 so no in-flight ds_read when its buffer is overwritten. Fully
// unrolled: all buffer indices / waitcnt immediates are literals.
// Compute body, dc-chain order, tie-break order identical to R6/R11 ->
// scores/argmin bit-identical.

typedef short v8s __attribute__((ext_vector_type(8)));
typedef float v4f __attribute__((ext_vector_type(4)));

__device__ inline unsigned short f2bf(float f) {  // RNE fp32->bf16
    uint32_t u = __float_as_uint(f);
    return (unsigned short)((u + 0x7fffu + ((u >> 16) & 1u)) >> 16);
}

// ---- Kernel 1: E -> SWIZZLED Ebf bf16 + nE + accum/done=0 ------------------
// Unit for (k, dc, g): U = (k>>4)*512 + dc*64 + g*16 + (k&15),
// holding elems d = dc*32 + g*8 .. +8. Coalesced 16B stores.
__global__ __launch_bounds__(256) void k_prep_e(const float* __restrict__ E,
                                                v8s* __restrict__ Esw,
                                                float* __restrict__ nE,
                                                float* __restrict__ accum,
                                                unsigned* __restrict__ done) {
    __shared__ float Ef[16][264];
    int q = blockIdx.x, tid = threadIdx.x;
    const float4* Ein = (const float4*)(E + ((size_t)q << 12));
#pragma unroll
    for (int i = 0; i < 4; i++) {
        int f4 = i * 256 + tid;
        int row = f4 >> 6, c4 = (f4 & 63) << 2;
        *(float4*)&Ef[row][c4] = Ein[f4];
    }
    __syncthreads();
    {
        int c = tid >> 4, l = tid & 15;
        float s = 0.f;
#pragma unroll
        for (int j = 0; j < 16; j++) { float v = Ef[c][l + 16 * j]; s += v * v; }
#pragma unroll
        for (int off = 1; off < 16; off <<= 1) s += __shfl_xor(s, off);
        if (l == 0) nE[q * 16 + c] = 0.5f * s;
    }
#pragma unroll
    for (int i = 0; i < 2; i++) {
        int u = tid + i * 256;
        int um = u & 15, ug = (u >> 4) & 3, udc = (u >> 6) & 7;
        int d0 = udc * 32 + ug * 8;
        union { v8s v; unsigned short s[8]; } pk;
#pragma unroll
        for (int e = 0; e < 8; e++) pk.s[e] = f2bf(Ef[um][d0 + e]);
        Esw[((size_t)q << 9) + u] = pk.v;
    }
    if (q == 0 && tid == 0) { accum[0] = 0.f; done[0] = 0u; }
}

// ---- Kernel 2: fused transpose+GEMM+argmin+gather+output+loss ---------------
__global__ __launch_bounds__(512) void k_main(
        const v8s* __restrict__ Esw,
        const float* __restrict__ nE,
        const float* __restrict__ z,
        const float* __restrict__ E,
        float* __restrict__ out,
        float* __restrict__ accum,
        unsigned* __restrict__ done) {
    __shared__ union {
        v8s    B[4][2048];          // 4 x 32 KB ring (A-tile 64KB = B[0..1])
        float4 Eg4[2048];           // epilogue swizzled tile (32 KB)
    } S;
    __shared__ float nEl[1024];
    __shared__ float nrmLds[128];
    __shared__ int   idxLds[128];
    __shared__ float w8[8];

    int tid = threadIdx.x;
    int lane = tid & 63, w = tid >> 6;         // 8 waves
    int g = lane >> 4, m = lane & 15;          // MFMA lane coords
    int R0 = blockIdx.x << 7;                  // 128 rows/block
    int b = R0 >> 10, hw0 = R0 & 1023;

    // ---- A-prep: z[b][0..256][hw0..hw0+128] -> swizzled bf16 LDS tile ------
    // Thread (q=tid&31, dblk=tid>>5) loads 16 d-rows x float4 at hw quad 4q,
    // repacks to 8 v8s (4 rows x 2 slots). Swizzle slot^((row^row>>2)&7)
    // spreads both writes and fragment reads across all 8 bank-quads.
    {
        int q = tid & 31, dblk = tid >> 5;     // hw = hw0+4q, d base = dblk*16
        const float* zp = z + ((size_t)b << 18) + hw0 + (q << 2);
#pragma unroll
        for (int s = 0; s < 2; s++) {
            float4 L[8];
#pragma unroll
            for (int j = 0; j < 8; j++)
                L[j] = *(const float4*)(zp + (size_t)(((dblk << 4) + (s << 3) + j) << 10));
            const float* Lf = (const float*)L;
            int slot = (dblk << 1) + s;
#pragma unroll
            for (int c = 0; c < 4; c++) {
                union { v8s v; unsigned short u[8]; } pk;
#pragma unroll
                for (int j = 0; j < 8; j++) pk.u[j] = f2bf(Lf[j * 4 + c]);
                int row = (q << 2) + c;
                int sw = slot ^ ((row ^ (row >> 2)) & 7);
                *(v8s*)((char*)&S + (row << 9) + (sw << 4)) = pk.v;
            }
        }
    }
#pragma unroll
    for (int i = 0; i < 2; i++) nEl[tid + i * 512] = nE[tid + i * 512];
    __syncthreads();                           // A-tile resident

    // A frags: 16 rows/wave, from LDS; row norm from the same bf16 values.
    v8s a[8];
    {
        int row = (w << 4) + m;
        int f = (row ^ (row >> 2)) & 7;
#pragma unroll
        for (int dc = 0; dc < 8; dc++) {
            int sw = ((dc << 2) + g) ^ f;
            a[dc] = *(const v8s*)((const char*)&S + (row << 9) + (sw << 4));
        }
        float nrm = 0.f;
#pragma unroll
        for (int dc = 0; dc < 8; dc++) {
            union { v8s v; unsigned short u[8]; } un; un.v = a[dc];
#pragma unroll
            for (int j = 0; j < 8; j++) {
                float v = __uint_as_float((uint32_t)un.u[j] << 16);
                nrm = fmaf(v, v, nrm);
            }
        }
        nrm += __shfl_xor(nrm, 16);            // reduce over g: full ||z_row||^2
        nrm += __shfl_xor(nrm, 32);
        if (g == 0) nrmLds[row] = nrm;
    }
    __syncthreads();                           // A-tile consumed; S free for B

    // staging: chunk = 2048 v8s (32 KB); wave w stages 4x 1KB slices
#define STAGE(ch, buf)                                                        \
    {                                                                         \
        _Pragma("unroll")                                                     \
        for (int j = 0; j < 4; j++) {                                         \
            __builtin_amdgcn_global_load_lds(                                 \
                (const __attribute__((address_space(1))) void*)               \
                    (Esw + ((size_t)(ch) << 11) + (j << 9) + (w << 6) + lane),\
                (__attribute__((address_space(3))) void*)                     \
                    &S.B[buf][(j << 9) + (w << 6)],                           \
                16, 0, 0);                                                    \
        }                                                                     \
    }

    float best[4]; int bidx[4];
#pragma unroll
    for (int r = 0; r < 4; r++) { best[r] = 3.4e38f; bidx[r] = 0; }

    // Per chunk: vmcnt(NW) -> barrier (ct resident everywhere) -> compute ->
    // lgkmcnt(0) -> barrier (readers done) -> stage ct+4 into ct's buffer.
#define CHUNK(CT, NW)                                                         \
    {                                                                         \
        asm volatile("s_waitcnt vmcnt(" #NW ")" ::: "memory");                \
        __builtin_amdgcn_s_barrier();                                         \
        float ne_[4];                                                         \
        _Pragma("unroll")                                                     \
        for (int t = 0; t < 4; t++) ne_[t] = nEl[((CT) << 6) + t * 16 + m];   \
        v4f acc_[4];                                                          \
        _Pragma("unroll")                                                     \
        for (int t = 0; t < 4; t++) acc_[t] = (v4f){0.f, 0.f, 0.f, 0.f};      \
        _Pragma("unroll")                                                     \
        for (int dc = 0; dc < 8; dc++) {                                      \
            _Pragma("unroll")                                                 \
            for (int t = 0; t < 4; t++) {                                     \
                v8s bf = S.B[(CT) & 3][t * 512 + dc * 64 + g * 16 + m];       \
                acc_[t] = __builtin_amdgcn_mfma_f32_16x16x32_bf16(            \
                              a[dc], bf, acc_[t], 0, 0, 0);                   \
            }                                                                 \
        }                                                                     \
        _Pragma("unroll")                                                     \
        for (int t = 0; t < 4; t++) {                                         \
            int code = ((CT) << 6) + t * 16 + m;                              \
            _Pragma("unroll")                                                 \
            for (int r = 0; r < 4; r++) {                                     \
                float s0 = ne_[t] - acc_[t][r];                               \
                if (s0 < best[r]) { best[r] = s0; bidx[r] = code; }           \
            }                                                                 \
        }                                                                     \
        asm volatile("s_waitcnt lgkmcnt(0)" ::: "memory");                    \
        __builtin_amdgcn_s_barrier();                                         \
        if ((CT) < 12) STAGE((CT) + 4, (CT) & 3);                             \
    }

    STAGE(0, 0); STAGE(1, 1); STAGE(2, 2); STAGE(3, 3);
    CHUNK(0, 12)  CHUNK(1, 12)  CHUNK(2, 12)  CHUNK(3, 12)
    CHUNK(4, 12)  CHUNK(5, 12)  CHUNK(6, 12)  CHUNK(7, 12)
    CHUNK(8, 12)  CHUNK(9, 12)  CHUNK(10, 12) CHUNK(11, 12)
    CHUNK(12, 12) CHUNK(13, 8)  CHUNK(14, 4)  CHUNK(15, 0)

    // winner reduce over 16 code-columns (pack: min => low score, low idx);
    // loss per row folded in: ||e* - z||^2 = 2*s* + ||z||^2.
    float lsum = 0.f;
#pragma unroll
    for (int r = 0; r < 4; r++) {
        uint32_t sb = __float_as_uint(best[r]);
        sb = (sb & 0x80000000u) ? ~sb : (sb | 0x80000000u);
        unsigned long long pk = ((unsigned long long)sb << 32) | (uint32_t)bidx[r];
#pragma unroll
        for (int off = 1; off < 16; off <<= 1) {
            unsigned long long o = __shfl_xor(pk, off);
            if (o < pk) pk = o;
        }
        int row = (w << 4) + (g << 2) + r;
        if (m == 0) {                          // C/D row = g*4 + r
            idxLds[row] = (int)(pk & 0xffffffffu);
            uint32_t t = (uint32_t)(pk >> 32);
            float sw = __uint_as_float((t & 0x80000000u) ? (t & 0x7fffffffu) : ~t);
            lsum += 2.0f * sw + nrmLds[row];
        }
    }
#pragma unroll
    for (int off = 1; off < 64; off <<= 1) lsum += __shfl_xor(lsum, off);
    if (lane == 0) w8[w] = lsum;
    __syncthreads();                           // winners visible; B free

    // epilogue: gather E rows + coalesced NCHW writes via XOR-swizzled tile.
    float* ob = out + ((size_t)b << 18);
    int hwl = tid & 31, dq0 = tid >> 5;        // dq0: 0..15
#pragma unroll 1
    for (int ph = 0; ph < 4; ph++) {
#pragma unroll
        for (int i = 0; i < 4; i++) {          // rows w + 8i (wave-uniform)
            int row = w + (i << 3);
            int k = idxLds[(ph << 5) + row];
            float4 v = ((const float4*)(E + ((size_t)k << 8)))[lane];
            S.Eg4[(row << 6) + (lane ^ row)] = v;
        }
        __syncthreads();
        int hwp = hw0 + (ph << 5) + hwl;
#pragma unroll
        for (int i = 0; i < 4; i++) {
            int dq = dq0 + (i << 4);
            float4 ev = S.Eg4[(hwl << 6) + (dq ^ hwl)];
            size_t o = ((size_t)dq << 12) + hwp;        // (4*dq)*1024 + hwp
            ob[o] = ev.x; ob[o + 1024] = ev.y; ob[o + 2048] = ev.z; ob[o + 3072] = ev.w;
        }
        __syncthreads();                        // tile reused next phase
    }

    // loss accumulate + fused scalar epilogue (last block writes outputs).
    if (tid == 0) {
        float s8 = 0.f;
#pragma unroll
        for (int i = 0; i < 8; i++) s8 += w8[i];
        atomicAdd(accum, s8);
        __threadfence();
        unsigned old = atomicAdd(done, 1u);
        if (old == 255u) {
            float s = atomicAdd(accum, 0.f) * (1.0f / 8388608.0f);
            out[8388608] = 1.25f * s;
            out[8388609] = s;
            out[8388610] = s;
        }
    }
#undef CHUNK
#undef STAGE
}

extern "C" void kernel_launch(void* const* d_in, const int* in_sizes, int n_in,
                              void* d_out, int out_size, void* d_ws, size_t ws_size,
                              hipStream_t stream) {
    const float* z = (const float*)d_in[0];
    const float* E = (const float*)d_in[1];
    char* ws = (char*)d_ws;
    v8s*      Esw   = (v8s*)(ws);                // 524,288 B
    float*    nE    = (float*)(ws + 524288);     //   4,096 B
    float*    accum = (float*)(ws + 528384);     //       4 B
    unsigned* done  = (unsigned*)(ws + 528388);  //       4 B
    float* out = (float*)d_out;

    hipLaunchKernelGGL(k_prep_e, dim3(64),  dim3(256), 0, stream, E, Esw, nE, accum, done);
    hipLaunchKernelGGL(k_main,   dim3(256), dim3(512), 0, stream,
                       Esw, nE, z, E, out, accum, done);
}

// Round 9
// 116.155 us; speedup vs baseline: 1.0199x; 1.0199x over previous
//
#include <hip/hip_runtime.h>
#include <hip/hip_bf16.h>
#include <stdint.h>

// VQ-VAE vector quantizer forward, MI355X (gfx950).
// z: [32,256,32,32] fp32 (NCHW), E: [1024,256] fp32.
// score(n,k) = 0.5*||e_k||^2 - <f_n,e_k>  (argmin-equivalent to d2)
// dots via bf16 MFMA 16x16x32 fp32-accum; gather exact fp32.
//
// R14: R6-R13 nulls (LDS traffic x0.5, barriers x0.5, counted vmcnt,
// occupancy x2/x4, zero-barrier L2-direct) mean the 46us k_main defies
// the phase model -- so this round MEASURES the split instead of
// theorizing: epilogue moves to its own kernel k_epi (2048 blocks, the
// grid shape a streaming op actually wants), k_main writes just the 128
// winner indices per block. k_main' duration in the top-5 table reveals
// the true fused-epilogue cost; k_epi streams 33.5MB at proper
// occupancy. Loss math stays in k_main (needs only s* and ||z||^2);
// k_epi block 0 writes the scalars (stream-ordered after k_main).
// Values / tie-break / summation order unchanged -> absmax identical.

typedef short v8s __attribute__((ext_vector_type(8)));
typedef float v4f __attribute__((ext_vector_type(4)));

__device__ inline unsigned short f2bf(float f) {  // RNE fp32->bf16
    uint32_t u = __float_as_uint(f);
    return (unsigned short)((u + 0x7fffu + ((u >> 16) & 1u)) >> 16);
}

// ---- Kernel 1: E -> SWIZZLED Ebf bf16 + nE + accum=0 -----------------------
// Unit for (k, dc, g): U = (k>>4)*512 + dc*64 + g*16 + (k&15),
// holding elems d = dc*32 + g*8 .. +8. Coalesced 16B stores.
__global__ __launch_bounds__(256) void k_prep_e(const float* __restrict__ E,
                                                v8s* __restrict__ Esw,
                                                float* __restrict__ nE,
                                                float* __restrict__ accum) {
    __shared__ float Ef[16][264];
    int q = blockIdx.x, tid = threadIdx.x;
    const float4* Ein = (const float4*)(E + ((size_t)q << 12));
#pragma unroll
    for (int i = 0; i < 4; i++) {
        int f4 = i * 256 + tid;
        int row = f4 >> 6, c4 = (f4 & 63) << 2;
        *(float4*)&Ef[row][c4] = Ein[f4];
    }
    __syncthreads();
    {
        int c = tid >> 4, l = tid & 15;
        float s = 0.f;
#pragma unroll
        for (int j = 0; j < 16; j++) { float v = Ef[c][l + 16 * j]; s += v * v; }
#pragma unroll
        for (int off = 1; off < 16; off <<= 1) s += __shfl_xor(s, off);
        if (l == 0) nE[q * 16 + c] = 0.5f * s;
    }
#pragma unroll
    for (int i = 0; i < 2; i++) {
        int u = tid + i * 256;
        int um = u & 15, ug = (u >> 4) & 3, udc = (u >> 6) & 7;
        int d0 = udc * 32 + ug * 8;
        union { v8s v; unsigned short s[8]; } pk;
#pragma unroll
        for (int e = 0; e < 8; e++) pk.s[e] = f2bf(Ef[um][d0 + e]);
        Esw[((size_t)q << 9) + u] = pk.v;
    }
    if (q == 0 && tid == 0) accum[0] = 0.f;
}

// ---- Kernel 2: fused transpose+GEMM+argmin+loss; winners -> idxG ------------
__global__ __launch_bounds__(512) void k_main(
        const v8s* __restrict__ Esw,
        const float* __restrict__ nE,
        const float* __restrict__ z,
        int* __restrict__ idxG,
        float* __restrict__ accum) {
    __shared__ union {
        v8s B[2][4096];             // 2 x 64 KB double-buffer (A-tile 64KB fits)
    } S;
    __shared__ float nEl[1024];
    __shared__ float nrmLds[128];
    __shared__ float w8[8];

    int tid = threadIdx.x;
    int lane = tid & 63, w = tid >> 6;         // 8 waves
    int g = lane >> 4, m = lane & 15;          // MFMA lane coords
    int R0 = blockIdx.x << 7;                  // 128 rows/block
    int b = R0 >> 10, hw0 = R0 & 1023;

    // ---- A-prep: z[b][0..256][hw0..hw0+128] -> swizzled bf16 LDS tile ------
    {
        int q = tid & 31, dblk = tid >> 5;     // hw = hw0+4q, d base = dblk*16
        const float* zp = z + ((size_t)b << 18) + hw0 + (q << 2);
#pragma unroll
        for (int s = 0; s < 2; s++) {
            float4 L[8];
#pragma unroll
            for (int j = 0; j < 8; j++)
                L[j] = *(const float4*)(zp + (size_t)(((dblk << 4) + (s << 3) + j) << 10));
            const float* Lf = (const float*)L;
            int slot = (dblk << 1) + s;
#pragma unroll
            for (int c = 0; c < 4; c++) {
                union { v8s v; unsigned short u[8]; } pk;
#pragma unroll
                for (int j = 0; j < 8; j++) pk.u[j] = f2bf(Lf[j * 4 + c]);
                int row = (q << 2) + c;
                int sw = slot ^ ((row ^ (row >> 2)) & 7);
                *(v8s*)((char*)&S + (row << 9) + (sw << 4)) = pk.v;
            }
        }
    }
#pragma unroll
    for (int i = 0; i < 2; i++) nEl[tid + i * 512] = nE[tid + i * 512];
    __syncthreads();                           // A-tile resident

    // A frags: 16 rows/wave, from LDS; row norm from the same bf16 values.
    v8s a[8];
    {
        int row = (w << 4) + m;
        int f = (row ^ (row >> 2)) & 7;
#pragma unroll
        for (int dc = 0; dc < 8; dc++) {
            int sw = ((dc << 2) + g) ^ f;
            a[dc] = *(const v8s*)((const char*)&S + (row << 9) + (sw << 4));
        }
        float nrm = 0.f;
#pragma unroll
        for (int dc = 0; dc < 8; dc++) {
            union { v8s v; unsigned short u[8]; } un; un.v = a[dc];
#pragma unroll
            for (int j = 0; j < 8; j++) {
                float v = __uint_as_float((uint32_t)un.u[j] << 16);
                nrm = fmaf(v, v, nrm);
            }
        }
        nrm += __shfl_xor(nrm, 16);            // reduce over g: full ||z_row||^2
        nrm += __shfl_xor(nrm, 32);
        if (g == 0) nrmLds[row] = nrm;
    }
    __syncthreads();                           // A-tile consumed; S free for B

    // contiguous staging: chunk = 4096 v8s (64 KB); thread stages j*512+tid
#define STAGE(ch, buf)                                                        \
    {                                                                         \
        _Pragma("unroll")                                                     \
        for (int j = 0; j < 8; j++) {                                         \
            __builtin_amdgcn_global_load_lds(                                 \
                (const __attribute__((address_space(1))) void*)               \
                    (Esw + ((size_t)(ch) << 12) + (j << 9) + (w << 6) + lane),\
                (__attribute__((address_space(3))) void*)                     \
                    &S.B[buf][(j << 9) + (w << 6)],                           \
                16, 0, 0);                                                    \
        }                                                                     \
    }

    float best[4]; int bidx[4];
#pragma unroll
    for (int r = 0; r < 4; r++) { best[r] = 3.4e38f; bidx[r] = 0; }

    STAGE(0, 0);
#pragma unroll 2
    for (int ct = 0; ct < 8; ct++) {
        int cur = ct & 1;                      // static after unroll 2
        __syncthreads();                       // chunk ct resident
        if (ct < 7) STAGE(ct + 1, cur ^ 1);
        float ne[8];
#pragma unroll
        for (int t = 0; t < 8; t++) ne[t] = nEl[(ct << 7) + (t << 4) + m];
        v4f acc[8];
#pragma unroll
        for (int t = 0; t < 8; t++) acc[t] = (v4f){0.f, 0.f, 0.f, 0.f};
#pragma unroll
        for (int dc = 0; dc < 8; dc++) {       // 8 indep chains/wave
#pragma unroll
            for (int t = 0; t < 8; t++) {
                v8s bf = S.B[cur][t * 512 + dc * 64 + g * 16 + m];
                acc[t] = __builtin_amdgcn_mfma_f32_16x16x32_bf16(a[dc], bf, acc[t], 0, 0, 0);
            }
        }
#pragma unroll
        for (int t = 0; t < 8; t++) {          // ascending code: tie -> low idx
            int code = (ct << 7) + (t << 4) + m;
#pragma unroll
            for (int r = 0; r < 4; r++) {
                float s0 = ne[t] - acc[t][r];
                if (s0 < best[r]) { best[r] = s0; bidx[r] = code; }
            }
        }
    }

    // winner reduce over 16 code-columns (pack: min => low score, low idx);
    // winners -> global idx; loss folded in: ||e* - z||^2 = 2*s* + ||z||^2.
    float lsum = 0.f;
#pragma unroll
    for (int r = 0; r < 4; r++) {
        uint32_t sb = __float_as_uint(best[r]);
        sb = (sb & 0x80000000u) ? ~sb : (sb | 0x80000000u);
        unsigned long long pk = ((unsigned long long)sb << 32) | (uint32_t)bidx[r];
#pragma unroll
        for (int off = 1; off < 16; off <<= 1) {
            unsigned long long o = __shfl_xor(pk, off);
            if (o < pk) pk = o;
        }
        int row = (w << 4) + (g << 2) + r;
        if (m == 0) {                          // C/D row = g*4 + r
            idxG[R0 + row] = (int)(pk & 0xffffffffu);
            uint32_t t = (uint32_t)(pk >> 32);
            float sw = __uint_as_float((t & 0x80000000u) ? (t & 0x7fffffffu) : ~t);
            lsum += 2.0f * sw + nrmLds[row];
        }
    }
#pragma unroll
    for (int off = 1; off < 64; off <<= 1) lsum += __shfl_xor(lsum, off);
    if (lane == 0) w8[w] = lsum;
    __syncthreads();
    if (tid == 0) {
        float s8 = 0.f;
#pragma unroll
        for (int i = 0; i < 8; i++) s8 += w8[i];
        atomicAdd(accum, s8);
    }
#undef STAGE
}

// ---- Kernel 3: epilogue gather + NCHW write, proper streaming grid ----------
// Block j owns (b = j>>6, d-quad d0 = (j&63)*4): 4 d-rows x 1024 hw.
// Thread t: hw quad 4t -> int4 idx load, 4x16B E-gathers (L2-resident),
// in-register 4x4 transpose, 4 coalesced float4 row-stores.
__global__ __launch_bounds__(256) void k_epi(const int* __restrict__ idxG,
                                             const float* __restrict__ E,
                                             const float* __restrict__ accum,
                                             float* __restrict__ out) {
    int j = blockIdx.x, t = threadIdx.x;
    int b = j >> 6, d0 = (j & 63) << 2;
    int4 kk = ((const int4*)(idxG + (b << 10)))[t];
    float4 e0 = *(const float4*)(E + ((size_t)kk.x << 8) + d0);
    float4 e1 = *(const float4*)(E + ((size_t)kk.y << 8) + d0);
    float4 e2 = *(const float4*)(E + ((size_t)kk.z << 8) + d0);
    float4 e3 = *(const float4*)(E + ((size_t)kk.w << 8) + d0);
    const float* p0 = &e0.x; const float* p1 = &e1.x;
    const float* p2 = &e2.x; const float* p3 = &e3.x;
    float* ob = out + ((size_t)b << 18) + ((size_t)d0 << 10) + (t << 2);
#pragma unroll
    for (int i = 0; i < 4; i++) {
        float4 v; v.x = p0[i]; v.y = p1[i]; v.z = p2[i]; v.w = p3[i];
        *(float4*)(ob + (size_t)i * 1024) = v;
    }
    if (j == 0 && t == 0) {                    // stream-ordered after k_main
        float s = atomicAdd((float*)accum, 0.f) * (1.0f / 8388608.0f);
        out[8388608] = 1.25f * s;
        out[8388609] = s;
        out[8388610] = s;
    }
}

extern "C" void kernel_launch(void* const* d_in, const int* in_sizes, int n_in,
                              void* d_out, int out_size, void* d_ws, size_t ws_size,
                              hipStream_t stream) {
    const float* z = (const float*)d_in[0];
    const float* E = (const float*)d_in[1];
    char* ws = (char*)d_ws;
    v8s*   Esw   = (v8s*)(ws);                   // 524,288 B
    float* nE    = (float*)(ws + 524288);        //   4,096 B
    float* accum = (float*)(ws + 528384);        //       4 B
    int*   idxG  = (int*)(ws + 532480);          // 131,072 B
    float* out = (float*)d_out;

    hipLaunchKernelGGL(k_prep_e, dim3(64),   dim3(256), 0, stream, E, Esw, nE, accum);
    hipLaunchKernelGGL(k_main,   dim3(256),  dim3(512), 0, stream,
                       Esw, nE, z, idxG, accum);
    hipLaunchKernelGGL(k_epi,    dim3(2048), dim3(256), 0, stream,
                       idxG, E, accum, out);
}